// Round 4
// baseline (347.061 us; speedup 1.0000x reference)
//
#include <hip/hip_runtime.h>
#include <hip/hip_bf16.h>
#include <cstdint>
#include <cstddef>

#define NROWS 8192
#define MCOLS 8192
#define DDIM  512
#define GRP   10

// k-chunk-major fp8 layout: byte (row,k) lives at
//   (k>>5) * CHUNK + row*32 + (k&31),  CHUNK = 8192*32 = 262144 bytes.
// Logical k-order is LINEAR within each 32-B chunk, chunks ascend in k.
#define CHUNK 262144

using f32x16 = __attribute__((ext_vector_type(16))) float;
using i32x4  = __attribute__((ext_vector_type(4))) int;
using i32x8  = __attribute__((ext_vector_type(8))) int;

// ---------------------------------------------------------------------------
// Kernel 1: cast fp32 rows -> fp8 e4m3 in k-chunk-major layout + per-row
// sum of squares. Block 2*NROWS computes the 10x10 group tables (t, c2).
// ---------------------------------------------------------------------------
__global__ __launch_bounds__(256) void prep_all(const float* __restrict__ X,
                                                const float* __restrict__ Z,
                                                uint16_t* __restrict__ Xa,
                                                uint16_t* __restrict__ Za,
                                                float* __restrict__ xx,
                                                float* __restrict__ zz,
                                                const float* __restrict__ emb,
                                                const float* __restrict__ sigma_p,
                                                const float* __restrict__ ls_p,
                                                const float* __restrict__ gdp_p,
                                                float2* __restrict__ tab) {
    int row = blockIdx.x;
    int t = threadIdx.x;
    if (row == 2 * NROWS) {            // table block
        if (t >= GRP * GRP) return;
        int a = t / GRP, b = t % GRP;
        float gd = 0.0f;
        #pragma unroll
        for (int g = 0; g < GRP; ++g) {
            float d = emb[a * GRP + g] - emb[b * GRP + g];
            gd += d * d;
        }
        float val = 1.0f / (fabsf(*gdp_p) * gd + 1.0f);
        float ls = *ls_p;
        float sg = *sigma_p;
        tab[t] = make_float2(-0.5f * val / (ls * ls),
                             sg * sg * powf(val, 0.5f * (float)DDIM));
        return;
    }
    const float* src;
    uint16_t* dst;
    float* sums;
    int r;
    if (row < NROWS) {
        r = row; src = X + (size_t)r * DDIM; dst = Xa; sums = xx;
    } else {
        r = row - NROWS; src = Z + (size_t)r * DDIM; dst = Za; sums = zz;
    }
    float2 p = ((const float2*)src)[t];          // 8B/lane coalesced
    int packed = __builtin_amdgcn_cvt_pk_fp8_f32(p.x, p.y, 0, false);
    // bytes k=2t,2t+1 -> chunk c=t>>4, u16 slot (t&15) of the row's 32B line
    dst[(size_t)(t >> 4) * (CHUNK / 2) + (size_t)r * 16 + (t & 15)] = (uint16_t)packed;
    float s = p.x * p.x + p.y * p.y;
    #pragma unroll
    for (int off = 32; off > 0; off >>= 1) s += __shfl_down(s, off, 64);
    __shared__ float ws[4];
    if ((t & 63) == 0) ws[t >> 6] = s;
    __syncthreads();
    if (t == 0) sums[r] = ws[0] + ws[1] + ws[2] + ws[3];
}

// ---------------------------------------------------------------------------
// Kernel 2: MX-scaled fp8 GEMM (X @ Z^T) + fused MGGP-RBF epilogue,
// ZERO-LDS VARIANT. A+B total 8 MiB fp8 -> fully L2-resident (per-XCD
// working set ~1.2 MB under the supertile remap), so LDS staging is pure
// overhead (Common-mistake #7 / m169: stage only what doesn't cache-fit).
// Each wave loads its own fragments global->VGPR; NO barriers anywhere;
// 12 independent waves/CU hide L2 latency (m114 wave-level overlap).
// k-chunk-major layout makes each fragment load 2 contiguous 512-B
// segments (coalesced) instead of 32 scattered 16-B pieces.
// Wave = 64x64 out as 2x2 of v_mfma_scale_f32_32x32x64_f8f6f4 (unit e8m0
// scales = 0x7F); operand mapping (row=lane&31, k-half=lane>>5, k linear)
// verified on HW by R3's pass. K fully unrolled: 8 steps x {8 dwordx4
// loads, 4 MFMA}, compiler free to software-pipeline across steps.
// (256,3): VGPR cap ~168; live ~ acc 64 + frags 32-64 + addr -> fits.
// ---------------------------------------------------------------------------
__global__ __launch_bounds__(256, 3) void mggp_gemm(
    const uint8_t* __restrict__ Xa, const uint8_t* __restrict__ Za,
    const float* __restrict__ xx, const float* __restrict__ zz,
    const int* __restrict__ gX, const int* __restrict__ gZ,
    const float2* __restrict__ tab,
    float* __restrict__ out) {

    const int tid  = threadIdx.x;
    const int lane = tid & 63;
    const int w    = tid >> 6;       // wave 0..3
    const int wr   = w >> 1;         // wave row (0..1)
    const int wc   = w & 1;          // wave col (0..1)
    const int cl   = lane & 31;      // row within 32-tile (A) / col (B)
    const int hi   = lane >> 5;      // k-half selector (verified R3)

    // 8x8 supertile remap (consecutive ids round-robin XCDs)
    const int lin = blockIdx.x;
    const int st  = lin >> 6;
    const int wi  = lin & 63;
    const int bx  = (st & 7) * 8 + (wi & 7);
    const int by  = (st >> 3) * 8 + (wi >> 3);
    const int brow = by * 128;
    const int bcol = bx * 128;

    f32x16 acc[2][2];
    #pragma unroll
    for (int ti = 0; ti < 2; ++ti)
        #pragma unroll
        for (int tj = 0; tj < 2; ++tj)
            #pragma unroll
            for (int e = 0; e < 16; ++e) acc[ti][tj][e] = 0.0f;

    // per-lane 32-bit voffsets into the k-chunk-major arrays
    int va[2], vb[2];
    #pragma unroll
    for (int ti = 0; ti < 2; ++ti)
        va[ti] = (brow + wr * 64 + ti * 32 + cl) * 32 + hi * CHUNK;
    #pragma unroll
    for (int tj = 0; tj < 2; ++tj)
        vb[tj] = (bcol + wc * 64 + tj * 32 + cl) * 32 + hi * CHUNK;

    #pragma unroll
    for (int kt = 0; kt < 8; ++kt) {             // K=64 per step
        const size_t ko = (size_t)kt * (2 * CHUNK);
        i32x8 aF[2], bF[2];
        #pragma unroll
        for (int ti = 0; ti < 2; ++ti) {
            const uint8_t* p = Xa + ko + va[ti];
            i32x4 lo = *(const i32x4*)p;
            i32x4 h4 = *(const i32x4*)(p + 16);
            aF[ti] = __builtin_shufflevector(lo, h4, 0, 1, 2, 3, 4, 5, 6, 7);
        }
        #pragma unroll
        for (int tj = 0; tj < 2; ++tj) {
            const uint8_t* p = Za + ko + vb[tj];
            i32x4 lo = *(const i32x4*)p;
            i32x4 h4 = *(const i32x4*)(p + 16);
            bF[tj] = __builtin_shufflevector(lo, h4, 0, 1, 2, 3, 4, 5, 6, 7);
        }
        #pragma unroll
        for (int ti = 0; ti < 2; ++ti)
            #pragma unroll
            for (int tj = 0; tj < 2; ++tj)
                acc[ti][tj] = __builtin_amdgcn_mfma_scale_f32_32x32x64_f8f6f4(
                    aF[ti], bF[tj], acc[ti][tj],
                    0, 0,                      // cbsz=fp8, blgp=fp8
                    0, 0x7F7F7F7F,             // opsel_a, scale_a = 1.0
                    0, 0x7F7F7F7F);            // opsel_b, scale_b = 1.0
    }

    // ---- epilogue: K = c2[ga][gb] * exp(dist * t[ga][gb]) ----
    // C/D (32x32 shapes): col = lane&31, row = (reg&3) + 8*(reg>>2) + 4*hi
    float zzv[2];
    int   gbv[2];
    #pragma unroll
    for (int tj = 0; tj < 2; ++tj) {
        int j = bcol + wc * 64 + tj * 32 + cl;
        zzv[tj] = zz[j];
        gbv[tj] = gZ[j];
    }
    #pragma unroll
    for (int ti = 0; ti < 2; ++ti) {
        #pragma unroll
        for (int reg = 0; reg < 16; ++reg) {
            int i = brow + wr * 64 + ti * 32 + (reg & 3) + 8 * (reg >> 2) + 4 * hi;
            float xxi = xx[i];
            int   ga  = gX[i] * GRP;
            float* orow = out + (size_t)i * MCOLS + bcol + wc * 64 + cl;
            #pragma unroll
            for (int tj = 0; tj < 2; ++tj) {
                float dot  = acc[ti][tj][reg];
                float dist = xxi + zzv[tj] - 2.0f * dot;
                float2 tc  = tab[ga + gbv[tj]];
                orow[tj * 32] = tc.y * __expf(dist * tc.x);
            }
        }
    }
}

// ---------------------------------------------------------------------------
extern "C" void kernel_launch(void* const* d_in, const int* in_sizes, int n_in,
                              void* d_out, int out_size, void* d_ws, size_t ws_size,
                              hipStream_t stream) {
    const float* X     = (const float*)d_in[0];
    const float* Z     = (const float*)d_in[1];
    const int*   gX    = (const int*)d_in[2];
    const int*   gZ    = (const int*)d_in[3];
    const float* emb   = (const float*)d_in[4];
    const float* sigma = (const float*)d_in[5];
    const float* ls    = (const float*)d_in[6];
    const float* gdp   = (const float*)d_in[7];

    char* ws = (char*)d_ws;
    const size_t XA_OFF  = 0;                              // 8192*512 = 4 MiB
    const size_t ZA_OFF  = XA_OFF + (size_t)NROWS * DDIM;  // 4 MiB
    const size_t XX_OFF  = ZA_OFF + (size_t)MCOLS * DDIM;
    const size_t ZZ_OFF  = XX_OFF + (size_t)NROWS * 4;
    const size_t TAB_OFF = ZZ_OFF + (size_t)MCOLS * 4;

    uint8_t* Xa  = (uint8_t*)(ws + XA_OFF);
    uint8_t* Za  = (uint8_t*)(ws + ZA_OFF);
    float* xx    = (float*)(ws + XX_OFF);
    float* zz    = (float*)(ws + ZZ_OFF);
    float2* tab  = (float2*)(ws + TAB_OFF);

    prep_all<<<2 * NROWS + 1, 256, 0, stream>>>(X, Z, (uint16_t*)Xa, (uint16_t*)Za,
                                                xx, zz, emb, sigma, ls, gdp, tab);
    mggp_gemm<<<4096, 256, 0, stream>>>(Xa, Za, xx, zz, gX, gZ, tab, (float*)d_out);
}